// Round 4
// baseline (255.563 us; speedup 1.0000x reference)
//
#include <hip/hip_runtime.h>
#include <stdint.h>

#define NHEADS 16
#define EDIM   1024
#define SEQ    2048
#define BATCH  4

typedef float  floatx4 __attribute__((ext_vector_type(4)));
typedef __bf16 bf16x8  __attribute__((ext_vector_type(8)));
typedef unsigned short u16;

__device__ __forceinline__ u16 f2bf(float f) {
  union { float f; unsigned int u; } v; v.f = f;
  return (u16)((v.u + 0x7fffu + ((v.u >> 16) & 1u)) >> 16);
}

// pack two floats -> (bf16(hi)<<16)|bf16(lo), round-half-up, 3 VALU ops
__device__ __forceinline__ unsigned int pkbf(float lo, float hi) {
  union { float f; unsigned int u; } a, c;
  a.f = lo; c.f = hi;
  return __builtin_amdgcn_perm(c.u + 0x8000u, a.u + 0x8000u, 0x07060302u);
}

__device__ __forceinline__ void gl2lds16(const u16* g, u16* l) {
  __builtin_amdgcn_global_load_lds(
      (const __attribute__((address_space(1))) unsigned int*)g,
      (__attribute__((address_space(3))) unsigned int*)l, 16, 0, 0);
}

// ---------------- fused fp32 -> bf16 conversion, 5 regions ----------------
__global__ void cvt_all(const float* __restrict__ x,  const float* __restrict__ wq,
                        const float* __restrict__ wk, const float* __restrict__ wv,
                        const float* __restrict__ wo, u16* __restrict__ xb,
                        u16* __restrict__ wqkv, u16* __restrict__ wob, float qscale) {
  const float* src; u16* dst; int n4; float sc = 1.f;
  switch (blockIdx.y) {
    case 0: src = x;  dst = xb;             n4 = 2097152; break;
    case 1: src = wq; dst = wqkv;           n4 = 262144; sc = qscale; break;
    case 2: src = wk; dst = wqkv + 1048576; n4 = 262144; break;
    case 3: src = wv; dst = wqkv + 2097152; n4 = 262144; break;
    default: src = wo; dst = wob;           n4 = 262144; break;
  }
  const int stride = gridDim.x * blockDim.x;
  for (int i = blockIdx.x * blockDim.x + threadIdx.x; i < n4; i += stride) {
    float4 f = ((const float4*)src)[i];
    uint2 o;
    o.x = pkbf(f.x * sc, f.y * sc);
    o.y = pkbf(f.z * sc, f.w * sc);
    ((uint2*)dst)[i] = o;
  }
}

// ---- GEMM (flipped): D[n][m] = A[n][K] dot B[m][K]; A=weights, B=activations
// MODE 0: A=Wqkv[3072][1024]: e<1024 -> Qb[s][e] (uint2), <2048 -> Kb, else
//         V written TRANSPOSED: Vt[b*1024 + hd][s_loc] (scalar u16).
// MODE 1: A=Wo[1024][1024]: fp32 float4 -> out[s][e].
template <int MODE>
__global__ __launch_bounds__(256, 3)
void gemm_tn(const u16* __restrict__ A, const u16* __restrict__ B,
             void* __restrict__ Cq, u16* __restrict__ Ck, u16* __restrict__ Cv,
             int Kdim) {
  __shared__ u16 As[128 * 64];
  __shared__ u16 Bs[128 * 64];
  const int tid  = threadIdx.x;
  const int w    = tid >> 6, lane = tid & 63;
  const int quad = lane >> 4, l15 = lane & 15;
  const int sr   = lane >> 3, sc8 = lane & 7;
  const int rowA0 = blockIdx.y * 128, rowB0 = blockIdx.x * 128;
  const int wrow  = (w >> 1) * 64,    wcol  = (w & 1) * 64;

  const floatx4 vzero = {0.f, 0.f, 0.f, 0.f};
  floatx4 acc[4][4];
#pragma unroll
  for (int mi = 0; mi < 4; ++mi)
#pragma unroll
    for (int ni = 0; ni < 4; ++ni) acc[mi][ni] = vzero;

  for (int k0 = 0; k0 < Kdim; k0 += 64) {
    __syncthreads();
#pragma unroll
    for (int i = 0; i < 4; ++i) {
      const int r = w * 32 + i * 8;   // 16B-chunk XOR swizzle by row&7 (= sr)
      gl2lds16(A + (size_t)(rowA0 + r + sr) * Kdim + k0 + ((sc8 ^ sr) * 8), As + r * 64);
      gl2lds16(B + (size_t)(rowB0 + r + sr) * Kdim + k0 + ((sc8 ^ sr) * 8), Bs + r * 64);
    }
    __syncthreads();
#pragma unroll
    for (int ks = 0; ks < 2; ++ks) {
      bf16x8 af[4], bfr[4];
#pragma unroll
      for (int mi = 0; mi < 4; ++mi)
        af[mi] = *(const bf16x8*)(As + (wrow + mi * 16 + l15) * 64 + (((ks * 4 + quad) ^ (l15 & 7)) * 8));
#pragma unroll
      for (int ni = 0; ni < 4; ++ni)
        bfr[ni] = *(const bf16x8*)(Bs + (wcol + ni * 16 + l15) * 64 + (((ks * 4 + quad) ^ (l15 & 7)) * 8));
#pragma unroll
      for (int mi = 0; mi < 4; ++mi)
#pragma unroll
        for (int ni = 0; ni < 4; ++ni)
          acc[mi][ni] = __builtin_amdgcn_mfma_f32_16x16x32_bf16(af[mi], bfr[ni], acc[mi][ni], 0, 0, 0);
    }
  }

  const int matid = rowA0 >> 10;  // uniform per block (MODE 0)
#pragma unroll
  for (int mi = 0; mi < 4; ++mi)
#pragma unroll
    for (int ni = 0; ni < 4; ++ni) {
      const int e0 = rowA0 + wrow + mi * 16 + quad * 4;   // 4 consecutive e in r
      const int s  = rowB0 + wcol + ni * 16 + l15;
      if (MODE == 1) {
        *(floatx4*)((float*)Cq + (size_t)s * 1024 + e0) = acc[mi][ni];
      } else {
        const int e_loc = e0 & 1023;
        if (matid < 2) {
          u16* dst = (matid == 0) ? (u16*)Cq : Ck;
          uint2 pk;
          pk.x = pkbf(acc[mi][ni][0], acc[mi][ni][1]);
          pk.y = pkbf(acc[mi][ni][2], acc[mi][ni][3]);
          *(uint2*)(dst + (size_t)s * 1024 + e_loc) = pk;
        } else {
          // V transposed: row = b*1024 + hd, col = s_loc
          const int b = s >> 11, s_loc = s & 2047;
#pragma unroll
          for (int r = 0; r < 4; ++r)
            Cv[(size_t)(b * 1024 + e_loc + r) * SEQ + s_loc] = f2bf(acc[mi][ni][r]);
        }
      }
    }
}

// ---------------- flash attention (causal, paired q-tiles, flipped MFMA) -----
// grid: x = bh (64), y = pair p (8). Block 512 = 8 waves; wave covers 16 q rows.
// P stays in registers: C-layout of S^T is reused directly as the PV B-operand
// under a t-permutation, with V A-fragments loaded with the SAME permutation
// (MFMA contraction is k-order agnostic). t_phys(ks,quad,j) =
//   32*ks + (j>=4)*16 + quad*4 + (j&3).
__global__ __launch_bounds__(512, 4)
void attn_fwd(const u16* __restrict__ Q, const u16* __restrict__ K,
              const u16* __restrict__ Vt, u16* __restrict__ Ctx) {
  __shared__ u16 Ks[128 * 64];      // K-tile [t][d], 16B-chunk XOR swizzle (t&7)
  __shared__ u16 Vs[64 * 128];      // Vt-tile [d][t], 16B-chunk XOR swizzle (d&15)
  const int tid  = threadIdx.x;
  const int w    = tid >> 6, lane = tid & 63;
  const int quad = lane >> 4, l15 = lane & 15;
  const int bh = blockIdx.x, b = bh >> 4, h = bh & 15;
  const int p  = blockIdx.y;
  const int qts[2] = {p, 15 - p};

  // Q B-fragments for both tiles (Q pre-scaled by 0.125*log2e via Wq cvt)
  bf16x8 bq[2][2];
#pragma unroll
  for (int tt = 0; tt < 2; ++tt)
#pragma unroll
    for (int ks = 0; ks < 2; ++ks) {
      const int qs = qts[tt] * 128 + w * 16 + l15;
      bq[tt][ks] = *(const bf16x8*)(Q + (size_t)(b * SEQ + qs) * EDIM + h * 64 + ks * 32 + quad * 8);
    }

  const floatx4 vzero = {0.f, 0.f, 0.f, 0.f};
  floatx4 o_acc[2][4];              // [tile][d-tile], O^T C-layout (col = q)
  float l_run[2] = {0.f, 0.f};
#pragma unroll
  for (int tt = 0; tt < 2; ++tt)
#pragma unroll
    for (int di = 0; di < 4; ++di) o_acc[tt][di] = vzero;

  const int krow = lane >> 3, kch = lane & 7;    // K staging: 8 rows x 8 chunks
  const int vrow = lane >> 4, vch = lane & 15;   // V staging: 4 rows x 16 chunks

  for (int kt = 0; kt <= qts[1]; ++kt) {
    __syncthreads();               // prior iter's K/V readers done
#pragma unroll
    for (int ii = 0; ii < 2; ++ii) {
      const int r0 = w * 16 + ii * 8;
      const int row = r0 + krow;
      gl2lds16(K + (size_t)(b * SEQ + kt * 128 + row) * EDIM + h * 64 + ((kch ^ (row & 7)) * 8),
               Ks + r0 * 64);
      const int d0 = w * 8 + ii * 4;
      const int dd = d0 + vrow;
      gl2lds16(Vt + (size_t)(bh * 64 + dd) * SEQ + kt * 128 + ((vch ^ (dd & 15)) * 8),
               Vs + d0 * 128);
    }
    __syncthreads();               // staging visible to all waves

#pragma unroll
    for (int tt = 1; tt >= 0; --tt) {
      if (tt == 0 && kt > qts[0]) continue;   // uniform branch

      // S^T = K * Q^T : D[t][q], A = K-tile rows(t), B = Q rows(q)
      floatx4 s_acc[8];
#pragma unroll
      for (int mi = 0; mi < 8; ++mi) s_acc[mi] = vzero;
#pragma unroll
      for (int ks = 0; ks < 2; ++ks) {
        bf16x8 ak[8];
#pragma unroll
        for (int mi = 0; mi < 8; ++mi)
          ak[mi] = *(const bf16x8*)(Ks + (mi * 16 + l15) * 64 + (((ks * 4 + quad) ^ (l15 & 7)) * 8));
#pragma unroll
        for (int mi = 0; mi < 8; ++mi)
          s_acc[mi] = __builtin_amdgcn_mfma_f32_16x16x32_bf16(ak[mi], bq[tt][ks], s_acc[mi], 0, 0, 0);
      }

      // causal mask on diagonal tile
      if (kt == qts[tt]) {
        const int q_loc = w * 16 + l15;
#pragma unroll
        for (int mi = 0; mi < 8; ++mi)
#pragma unroll
          for (int r = 0; r < 4; ++r) {
            const int t_loc = mi * 16 + quad * 4 + r;
            if (t_loc > q_loc) s_acc[mi][r] = -1e30f;
          }
      }

      // p = exp2(s'); pack directly into PV B-operand dwords (C-layout t-order)
      float ls = 0.f;
      unsigned int pk[4][4];        // [ks][dword]
#pragma unroll
      for (int mi = 0; mi < 8; ++mi) {
        float p0 = __builtin_amdgcn_exp2f(s_acc[mi][0]);
        float p1 = __builtin_amdgcn_exp2f(s_acc[mi][1]);
        float p2 = __builtin_amdgcn_exp2f(s_acc[mi][2]);
        float p3 = __builtin_amdgcn_exp2f(s_acc[mi][3]);
        ls += (p0 + p1) + (p2 + p3);
        pk[mi >> 1][(mi & 1) * 2 + 0] = pkbf(p0, p1);
        pk[mi >> 1][(mi & 1) * 2 + 1] = pkbf(p2, p3);
      }
      ls += __shfl_xor(ls, 16, 64);
      ls += __shfl_xor(ls, 32, 64);
      l_run[tt] += ls;

      // O^T += Vt * P^T with permuted k: va element j = V[d][t_phys(ks,quad,j)]
#pragma unroll
      for (int ks = 0; ks < 4; ++ks) {
        union { unsigned int u[4]; bf16x8 v; } pb;
        pb.u[0] = pk[ks][0]; pb.u[1] = pk[ks][1];
        pb.u[2] = pk[ks][2]; pb.u[3] = pk[ks][3];
        const int cA = ((ks * 4 + (quad >> 1)) ^ l15) * 8 + (quad & 1) * 4;
        const int cB = ((ks * 4 + 2 + (quad >> 1)) ^ l15) * 8 + (quad & 1) * 4;
#pragma unroll
        for (int di = 0; di < 4; ++di) {
          const u16* vrowp = Vs + (di * 16 + l15) * 128;
          union { uint2 u2[2]; bf16x8 v; } va;
          va.u2[0] = *(const uint2*)(vrowp + cA);
          va.u2[1] = *(const uint2*)(vrowp + cB);
          o_acc[tt][di] = __builtin_amdgcn_mfma_f32_16x16x32_bf16(va.v, pb.v, o_acc[tt][di], 0, 0, 0);
        }
      }
    }
  }

  // epilogue: O = O^T / l, packed 8B stores along d
#pragma unroll
  for (int tt = 0; tt < 2; ++tt) {
    const float rl = 1.f / l_run[tt];
    const int qs = qts[tt] * 128 + w * 16 + l15;
#pragma unroll
    for (int di = 0; di < 4; ++di) {
      uint2 ov;
      ov.x = pkbf(o_acc[tt][di][0] * rl, o_acc[tt][di][1] * rl);
      ov.y = pkbf(o_acc[tt][di][2] * rl, o_acc[tt][di][3] * rl);
      *(uint2*)(Ctx + (size_t)(b * SEQ + qs) * EDIM + h * 64 + di * 16 + quad * 4) = ov;
    }
  }
}

// ---------------- launch ----------------
extern "C" void kernel_launch(void* const* d_in, const int* in_sizes, int n_in,
                              void* d_out, int out_size, void* d_ws, size_t ws_size,
                              hipStream_t stream) {
  const float* x  = (const float*)d_in[0];
  const float* Wq = (const float*)d_in[1];
  const float* Wk = (const float*)d_in[2];
  const float* Wv = (const float*)d_in[3];
  const float* Wo = (const float*)d_in[4];
  float* out = (float*)d_out;
  u16* ws = (u16*)d_ws;

  const size_t ME = (size_t)BATCH * SEQ * EDIM;  // 8388608
  u16* Xb   = ws;                                // [8192][1024] bf16
  u16* Wqkv = Xb + ME;                           // [3072][1024]
  u16* Wob  = Wqkv + 3u * 1024 * 1024;           // [1024][1024]
  u16* Qb   = Wob + 1024u * 1024;                // [B,S,E] (pre-scaled)
  u16* Kb   = Qb + ME;
  u16* Vtr  = Kb + ME;                           // V^T: [b*1024 + h*64 + d][2048]
  u16* Ctx  = Vtr + ME;                          // ends at ~88 MB

  const float qscale = 0.125f * 1.44269504f;     // 1/sqrt(64) * log2(e)

  cvt_all<<<dim3(512, 5), 256, 0, stream>>>(x, Wq, Wk, Wv, Wo, Xb, Wqkv, Wob, qscale);
  gemm_tn<0><<<dim3(64, 24), 256, 0, stream>>>(Wqkv, Xb, (void*)Qb, Kb, Vtr, EDIM);
  attn_fwd<<<dim3(64, 8), 512, 0, stream>>>(Qb, Kb, Vtr, Ctx);
  gemm_tn<1><<<dim3(64, 8), 256, 0, stream>>>(Wob, Ctx, (void*)out, nullptr, nullptr, EDIM);
}

// Round 5
// 253.972 us; speedup vs baseline: 1.0063x; 1.0063x over previous
//
#include <hip/hip_runtime.h>
#include <stdint.h>

#define NHEADS 16
#define EDIM   1024
#define SEQ    2048
#define BATCH  4

typedef float  floatx4 __attribute__((ext_vector_type(4)));
typedef __bf16 bf16x8  __attribute__((ext_vector_type(8)));
typedef unsigned short u16;

__device__ __forceinline__ u16 f2bf(float f) {
  union { float f; unsigned int u; } v; v.f = f;
  return (u16)((v.u + 0x7fffu + ((v.u >> 16) & 1u)) >> 16);
}

// pack two floats -> (bf16(hi)<<16)|bf16(lo), round-half-up, 3 VALU ops
__device__ __forceinline__ unsigned int pkbf(float lo, float hi) {
  union { float f; unsigned int u; } a, c;
  a.f = lo; c.f = hi;
  return __builtin_amdgcn_perm(c.u + 0x8000u, a.u + 0x8000u, 0x07060302u);
}

__device__ __forceinline__ void gl2lds16(const u16* g, u16* l) {
  __builtin_amdgcn_global_load_lds(
      (const __attribute__((address_space(1))) unsigned int*)g,
      (__attribute__((address_space(3))) unsigned int*)l, 16, 0, 0);
}

// ---------------- fused fp32 -> bf16 conversion, 5 regions ----------------
__global__ void cvt_all(const float* __restrict__ x,  const float* __restrict__ wq,
                        const float* __restrict__ wk, const float* __restrict__ wv,
                        const float* __restrict__ wo, u16* __restrict__ xb,
                        u16* __restrict__ wqkv, u16* __restrict__ wob, float qscale) {
  const float* src; u16* dst; int n4; float sc = 1.f;
  switch (blockIdx.y) {
    case 0: src = x;  dst = xb;             n4 = 2097152; break;
    case 1: src = wq; dst = wqkv;           n4 = 262144; sc = qscale; break;
    case 2: src = wk; dst = wqkv + 1048576; n4 = 262144; break;
    case 3: src = wv; dst = wqkv + 2097152; n4 = 262144; break;
    default: src = wo; dst = wob;           n4 = 262144; break;
  }
  const int stride = gridDim.x * blockDim.x;
  for (int i = blockIdx.x * blockDim.x + threadIdx.x; i < n4; i += stride) {
    float4 f = ((const float4*)src)[i];
    uint2 o;
    o.x = pkbf(f.x * sc, f.y * sc);
    o.y = pkbf(f.z * sc, f.w * sc);
    ((uint2*)dst)[i] = o;
  }
}

// ---- GEMM: A=weights[n][K], B=activations[m][K].
// MODE 0, matid<2 (Q,K): D[e][s] orientation -> packed uint2 stores along e.
// MODE 0, matid==2 (V): operands swapped -> D[s][e] -> V^T packed uint2 along s.
// MODE 1: A=Wo: fp32 float4 -> out[s][e].
template <int MODE>
__global__ __launch_bounds__(256, 2)
void gemm_tn(const u16* __restrict__ A, const u16* __restrict__ B,
             void* __restrict__ Cq, u16* __restrict__ Ck, u16* __restrict__ Cv,
             int Kdim) {
  __shared__ u16 As[128 * 64];
  __shared__ u16 Bs[128 * 64];
  const int tid  = threadIdx.x;
  const int w    = tid >> 6, lane = tid & 63;
  const int quad = lane >> 4, l15 = lane & 15;
  const int sr   = lane >> 3, sc8 = lane & 7;
  const int rowA0 = blockIdx.y * 128, rowB0 = blockIdx.x * 128;
  const int wrow  = (w >> 1) * 64,    wcol  = (w & 1) * 64;
  const int matid = (MODE == 0) ? (rowA0 >> 10) : 1;  // uniform per block

  const floatx4 vzero = {0.f, 0.f, 0.f, 0.f};
  floatx4 acc[4][4];
#pragma unroll
  for (int mi = 0; mi < 4; ++mi)
#pragma unroll
    for (int ni = 0; ni < 4; ++ni) acc[mi][ni] = vzero;

  for (int k0 = 0; k0 < Kdim; k0 += 64) {
    __syncthreads();
#pragma unroll
    for (int i = 0; i < 4; ++i) {
      const int r = w * 32 + i * 8;   // 16B-chunk XOR swizzle by row&7 (= sr)
      gl2lds16(A + (size_t)(rowA0 + r + sr) * Kdim + k0 + ((sc8 ^ sr) * 8), As + r * 64);
      gl2lds16(B + (size_t)(rowB0 + r + sr) * Kdim + k0 + ((sc8 ^ sr) * 8), Bs + r * 64);
    }
    __syncthreads();
#pragma unroll
    for (int ks = 0; ks < 2; ++ks) {
      bf16x8 af[4], bfr[4];
#pragma unroll
      for (int mi = 0; mi < 4; ++mi)
        af[mi] = *(const bf16x8*)(As + (wrow + mi * 16 + l15) * 64 + (((ks * 4 + quad) ^ (l15 & 7)) * 8));
#pragma unroll
      for (int ni = 0; ni < 4; ++ni)
        bfr[ni] = *(const bf16x8*)(Bs + (wcol + ni * 16 + l15) * 64 + (((ks * 4 + quad) ^ (l15 & 7)) * 8));
      if (MODE == 0 && matid == 2) {
        // swapped: A-operand = activations (m=s), B-operand = weights (n=e)
#pragma unroll
        for (int mi = 0; mi < 4; ++mi)
#pragma unroll
          for (int ni = 0; ni < 4; ++ni)
            acc[mi][ni] = __builtin_amdgcn_mfma_f32_16x16x32_bf16(bfr[ni], af[mi], acc[mi][ni], 0, 0, 0);
      } else {
#pragma unroll
        for (int mi = 0; mi < 4; ++mi)
#pragma unroll
          for (int ni = 0; ni < 4; ++ni)
            acc[mi][ni] = __builtin_amdgcn_mfma_f32_16x16x32_bf16(af[mi], bfr[ni], acc[mi][ni], 0, 0, 0);
      }
    }
  }

#pragma unroll
  for (int mi = 0; mi < 4; ++mi)
#pragma unroll
    for (int ni = 0; ni < 4; ++ni) {
      if (MODE == 1) {
        const int e0 = rowA0 + wrow + mi * 16 + quad * 4;
        const int s  = rowB0 + wcol + ni * 16 + l15;
        *(floatx4*)((float*)Cq + (size_t)s * 1024 + e0) = acc[mi][ni];
      } else if (matid < 2) {
        const int e0 = rowA0 + wrow + mi * 16 + quad * 4;   // 4 consecutive e
        const int s  = rowB0 + wcol + ni * 16 + l15;
        const int e_loc = e0 & 1023;
        u16* dst = (matid == 0) ? (u16*)Cq : Ck;
        uint2 pk;
        pk.x = pkbf(acc[mi][ni][0], acc[mi][ni][1]);
        pk.y = pkbf(acc[mi][ni][2], acc[mi][ni][3]);
        *(uint2*)(dst + (size_t)s * 1024 + e_loc) = pk;
      } else {
        // swapped orientation: rows = s (4 consecutive), col = e
        const int e_loc = (rowA0 + wrow + mi * 16 + l15) & 1023;
        const int s_full = rowB0 + wcol + ni * 16 + quad * 4;
        const int bb = s_full >> 11, s_loc = s_full & 2047;
        uint2 pk;
        pk.x = pkbf(acc[mi][ni][0], acc[mi][ni][1]);
        pk.y = pkbf(acc[mi][ni][2], acc[mi][ni][3]);
        *(uint2*)(Cv + (size_t)(bb * 1024 + e_loc) * SEQ + s_loc) = pk;
      }
    }
}

// ---------------- flash attention (causal, paired q-tiles, double-buffered) --
// grid: x = bh (64), y = pair p (8). Block 512 = 8 waves; wave covers 16 q rows.
// K/V double-buffered in LDS; one barrier per kt-iter; prefetch kt+1 issued
// right after the barrier so loads overlap the full tile compute.
// P stays in registers (C-layout reused as PV B-operand under t-permutation
// t_phys(ks,quad,j) = 32ks + 16(j>=4) + 4quad + (j&3); V A-frags load with the
// same permutation).
__global__ __launch_bounds__(512, 4)
void attn_fwd(const u16* __restrict__ Q, const u16* __restrict__ K,
              const u16* __restrict__ Vt, u16* __restrict__ Ctx) {
  __shared__ u16 Ks[2][128 * 64];   // [t][d], 16B-chunk XOR swizzle (t&7)
  __shared__ u16 Vs[2][64 * 128];   // [d][t], 16B-chunk XOR swizzle (d&15)
  const int tid  = threadIdx.x;
  const int w    = tid >> 6, lane = tid & 63;
  const int quad = lane >> 4, l15 = lane & 15;
  const int bh = blockIdx.x, b = bh >> 4, h = bh & 15;
  const int p  = blockIdx.y;
  const int qts[2] = {p, 15 - p};
  const int kmax = qts[1];

  // Q B-fragments for both tiles (Q pre-scaled by 0.125*log2e via Wq cvt)
  bf16x8 bq[2][2];
#pragma unroll
  for (int tt = 0; tt < 2; ++tt)
#pragma unroll
    for (int ks = 0; ks < 2; ++ks) {
      const int qs = qts[tt] * 128 + w * 16 + l15;
      bq[tt][ks] = *(const bf16x8*)(Q + (size_t)(b * SEQ + qs) * EDIM + h * 64 + ks * 32 + quad * 8);
    }

  const floatx4 vzero = {0.f, 0.f, 0.f, 0.f};
  floatx4 o_acc[2][4];              // [tile][d-tile], O^T C-layout (col = q)
  float l_run[2] = {0.f, 0.f};
#pragma unroll
  for (int tt = 0; tt < 2; ++tt)
#pragma unroll
    for (int di = 0; di < 4; ++di) o_acc[tt][di] = vzero;

  const int krow = lane >> 3, kch = lane & 7;    // K staging: 8 rows x 8 chunks
  const int vrow = lane >> 4, vch = lane & 15;   // V staging: 4 rows x 16 chunks

  // stage helper (inlined twice): loads tile kt into buffer buf
#define STAGE_KV(buf, ktn)                                                          \
  {                                                                                 \
    _Pragma("unroll")                                                               \
    for (int ii = 0; ii < 2; ++ii) {                                                \
      const int r0 = w * 16 + ii * 8;                                               \
      const int row = r0 + krow;                                                    \
      gl2lds16(K + (size_t)(b * SEQ + (ktn) * 128 + row) * EDIM + h * 64 +          \
                   ((kch ^ (row & 7)) * 8),                                         \
               &Ks[buf][r0 * 64]);                                                  \
      const int d0 = w * 8 + ii * 4;                                                \
      const int dd = d0 + vrow;                                                     \
      gl2lds16(Vt + (size_t)(bh * 64 + dd) * SEQ + (ktn) * 128 +                    \
                   ((vch ^ (dd & 15)) * 8),                                         \
               &Vs[buf][d0 * 128]);                                                 \
    }                                                                               \
  }

  STAGE_KV(0, 0);                   // prefetch first tile

  for (int kt = 0; kt <= kmax; ++kt) {
    const int cur = kt & 1;
    __syncthreads();                // buf[cur] loads drained; buf[cur^1] readers done
    if (kt < kmax) STAGE_KV(cur ^ 1, kt + 1);
    const u16* Ksc = &Ks[cur][0];
    const u16* Vsc = &Vs[cur][0];

#pragma unroll
    for (int tt = 1; tt >= 0; --tt) {
      if (tt == 0 && kt > qts[0]) continue;   // uniform branch

      // S^T = K * Q^T : D[t][q], A = K-tile rows(t), B = Q rows(q)
      floatx4 s_acc[8];
#pragma unroll
      for (int mi = 0; mi < 8; ++mi) s_acc[mi] = vzero;
#pragma unroll
      for (int ks = 0; ks < 2; ++ks) {
        bf16x8 ak[8];
#pragma unroll
        for (int mi = 0; mi < 8; ++mi)
          ak[mi] = *(const bf16x8*)(Ksc + (mi * 16 + l15) * 64 + (((ks * 4 + quad) ^ (l15 & 7)) * 8));
#pragma unroll
        for (int mi = 0; mi < 8; ++mi)
          s_acc[mi] = __builtin_amdgcn_mfma_f32_16x16x32_bf16(ak[mi], bq[tt][ks], s_acc[mi], 0, 0, 0);
      }

      // causal mask on diagonal tile
      if (kt == qts[tt]) {
        const int q_loc = w * 16 + l15;
#pragma unroll
        for (int mi = 0; mi < 8; ++mi)
#pragma unroll
          for (int r = 0; r < 4; ++r) {
            const int t_loc = mi * 16 + quad * 4 + r;
            if (t_loc > q_loc) s_acc[mi][r] = -1e30f;
          }
      }

      // p = exp2(s'); pack directly into PV B-operand dwords (C-layout t-order)
      float ls = 0.f;
      unsigned int pk[4][4];        // [ks][dword]
#pragma unroll
      for (int mi = 0; mi < 8; ++mi) {
        float p0 = __builtin_amdgcn_exp2f(s_acc[mi][0]);
        float p1 = __builtin_amdgcn_exp2f(s_acc[mi][1]);
        float p2 = __builtin_amdgcn_exp2f(s_acc[mi][2]);
        float p3 = __builtin_amdgcn_exp2f(s_acc[mi][3]);
        ls += (p0 + p1) + (p2 + p3);
        pk[mi >> 1][(mi & 1) * 2 + 0] = pkbf(p0, p1);
        pk[mi >> 1][(mi & 1) * 2 + 1] = pkbf(p2, p3);
      }
      ls += __shfl_xor(ls, 16, 64);
      ls += __shfl_xor(ls, 32, 64);
      l_run[tt] += ls;

      // O^T += Vt * P^T with permuted k: va element j = V[d][t_phys(ks,quad,j)]
#pragma unroll
      for (int ks = 0; ks < 4; ++ks) {
        union { unsigned int u[4]; bf16x8 v; } pb;
        pb.u[0] = pk[ks][0]; pb.u[1] = pk[ks][1];
        pb.u[2] = pk[ks][2]; pb.u[3] = pk[ks][3];
        const int cA = ((ks * 4 + (quad >> 1)) ^ l15) * 8 + (quad & 1) * 4;
        const int cB = ((ks * 4 + 2 + (quad >> 1)) ^ l15) * 8 + (quad & 1) * 4;
#pragma unroll
        for (int di = 0; di < 4; ++di) {
          const u16* vrowp = Vsc + (di * 16 + l15) * 128;
          union { uint2 u2[2]; bf16x8 v; } va;
          va.u2[0] = *(const uint2*)(vrowp + cA);
          va.u2[1] = *(const uint2*)(vrowp + cB);
          o_acc[tt][di] = __builtin_amdgcn_mfma_f32_16x16x32_bf16(va.v, pb.v, o_acc[tt][di], 0, 0, 0);
        }
      }
    }
  }

  // epilogue: O = O^T / l, packed 8B stores along d
#pragma unroll
  for (int tt = 0; tt < 2; ++tt) {
    const float rl = 1.f / l_run[tt];
    const int qs = qts[tt] * 128 + w * 16 + l15;
#pragma unroll
    for (int di = 0; di < 4; ++di) {
      uint2 ov;
      ov.x = pkbf(o_acc[tt][di][0] * rl, o_acc[tt][di][1] * rl);
      ov.y = pkbf(o_acc[tt][di][2] * rl, o_acc[tt][di][3] * rl);
      *(uint2*)(Ctx + (size_t)(b * SEQ + qs) * EDIM + h * 64 + di * 16 + quad * 4) = ov;
    }
  }
#undef STAGE_KV
}

// ---------------- launch ----------------
extern "C" void kernel_launch(void* const* d_in, const int* in_sizes, int n_in,
                              void* d_out, int out_size, void* d_ws, size_t ws_size,
                              hipStream_t stream) {
  const float* x  = (const float*)d_in[0];
  const float* Wq = (const float*)d_in[1];
  const float* Wk = (const float*)d_in[2];
  const float* Wv = (const float*)d_in[3];
  const float* Wo = (const float*)d_in[4];
  float* out = (float*)d_out;
  u16* ws = (u16*)d_ws;

  const size_t ME = (size_t)BATCH * SEQ * EDIM;  // 8388608
  u16* Xb   = ws;                                // [8192][1024] bf16
  u16* Wqkv = Xb + ME;                           // [3072][1024]
  u16* Wob  = Wqkv + 3u * 1024 * 1024;           // [1024][1024]
  u16* Qb   = Wob + 1024u * 1024;                // [B,S,E] (pre-scaled)
  u16* Kb   = Qb + ME;
  u16* Vtr  = Kb + ME;                           // V^T: [b*1024 + h*64 + d][2048]
  u16* Ctx  = Vtr + ME;                          // ends at ~88 MB

  const float qscale = 0.125f * 1.44269504f;     // 1/sqrt(64) * log2(e)

  cvt_all<<<dim3(512, 5), 256, 0, stream>>>(x, Wq, Wk, Wv, Wo, Xb, Wqkv, Wob, qscale);
  gemm_tn<0><<<dim3(64, 24), 256, 0, stream>>>(Wqkv, Xb, (void*)Qb, Kb, Vtr, EDIM);
  attn_fwd<<<dim3(64, 8), 512, 0, stream>>>(Qb, Kb, Vtr, Ctx);
  gemm_tn<1><<<dim3(64, 8), 256, 0, stream>>>(Wob, Ctx, (void*)out, nullptr, nullptr, EDIM);
}